// Round 8
// baseline (153.780 us; speedup 1.0000x reference)
//
#include <hip/hip_runtime.h>

#define BC 88                        // B*C channels
#define NVOX 262144                  // 64^3
#define KBINS 20
#define NEDGE 21                     // contiguous bin edges e[0..20]
#define THREADS 256
#define NBLOCKS 2048                 // 11 chunks/block covers 22528 chunks exactly
#define CPB 11                       // chunks (1024 elems = 256 float4) per block
#define CPC 256                      // chunks per channel

// Ballot-popcount CDF: c[j] = #(a < e[j]) - #(b < e[j]) held as wave-uniform
// SGPR counters, accumulated via v_cmp (VALU) + s_bcnt1/s_add (SALU pipe).
// ZERO LDS in the inner loop (DS pipe was the 38us wall in R2/R4/R6/R7),
// and 2 VALU/edge-pair vs R3's 6 (R3's 93us failure mode).
__global__ void __launch_bounds__(THREADS, 8)
binloss_main(const float* __restrict__ inp, const float* __restrict__ tar,
             const float* __restrict__ br, int* __restrict__ g_cdf,
             float* __restrict__ partials)
{
    __shared__ float wsum[THREADS / 64];
    const int tid  = threadIdx.x;
    const int lane = tid & 63;

    // edges: uniform loads -> SGPRs (exact values, exact reference semantics)
    float e[NEDGE];
#pragma unroll
    for (int j = 0; j < KBINS; ++j) e[j] = br[2 * j];
    e[KBINS] = br[2 * KBINS - 1];

    const int fc  = blockIdx.x * CPB;
    const int ch0 = fc >> 8;                  // / CPC
    const int rem = fc & (CPC - 1);
    const int n1  = (rem + CPB > CPC) ? (CPC - rem) : CPB;  // chunks in ch0

    const float4* pa = (const float4*)inp + (size_t)fc * 256 + tid;
    const float4* pb = (const float4*)tar + (size_t)fc * 256 + tid;

    int c[NEDGE];                             // wave-uniform -> SGPRs
#pragma unroll
    for (int j = 0; j < NEDGE; ++j) c[j] = 0;

    float s_lin = 0.f, s_quad = 0.f;
    int cur = ch0;

    float4 a = pa[0], b = pb[0];              // 1-deep prefetch pipeline
#pragma unroll
    for (int k = 0; k < CPB; ++k) {
        float4 an, bn;
        if (k < CPB - 1) { an = pa[(k + 1) * 256]; bn = pb[(k + 1) * 256]; }

        if (k == n1) {                        // uniform: channel boundary
            if (lane == 0)
#pragma unroll
                for (int j = 0; j < NEDGE; ++j)
                    atomicAdd(&g_cdf[cur * NEDGE + j], c[j]);
#pragma unroll
            for (int j = 0; j < NEDGE; ++j) c[j] = 0;
            cur = ch0 + 1;
        }

#pragma unroll
        for (int q = 0; q < 4; ++q) {
            float av = (&a.x)[q], bv = (&b.x)[q];
            float d = fabsf(av - bv);
            s_lin += fmaxf(d, 1.0f);          // -1 hoisted out
            float m = fminf(d, 1.0f);
            s_quad  = __builtin_fmaf(m, m, s_quad);
#pragma unroll
            for (int j = 0; j < NEDGE; ++j) {
                c[j] += (int)__popcll(__ballot(av < e[j]));
                c[j] -= (int)__popcll(__ballot(bv < e[j]));
            }
        }
        a = an; b = bn;
    }

    if (lane == 0)                            // flush last (or only) segment
#pragma unroll
        for (int j = 0; j < NEDGE; ++j)
            atomicAdd(&g_cdf[cur * NEDGE + j], c[j]);

    // SmoothL1 wave(64) + cross-wave reduce
    float sl1 = (s_lin - (float)(CPB * 4)) + 0.5f * s_quad;
#pragma unroll
    for (int off = 32; off > 0; off >>= 1) sl1 += __shfl_down(sl1, off, 64);
    if (lane == 0) wsum[tid >> 6] = sl1;
    __syncthreads();
    if (tid == 0)
        partials[blockIdx.x] = wsum[0] + wsum[1] + wsum[2] + wsum[3];
}

__global__ void __launch_bounds__(256)
binloss_final(const int* __restrict__ g_cdf, const float* __restrict__ partials,
              float* __restrict__ out)
{
    __shared__ double r1[256];
    __shared__ double r2[256];
    const int tid = threadIdx.x;
    double s1 = 0.0, s2 = 0.0;
    for (int i = tid; i < NBLOCKS; i += 256) s1 += (double)partials[i];
    for (int i = tid; i < BC * KBINS; i += 256) {
        int ch = i / KBINS, k = i - ch * KBINS;
        int hd = g_cdf[ch * NEDGE + k + 1] - g_cdf[ch * NEDGE + k];
        s2 += fabs((double)hd);
    }
    r1[tid] = s1; r2[tid] = s2;
    __syncthreads();
    for (int off = 128; off > 0; off >>= 1) {
        if (tid < off) { r1[tid] += r1[tid + off]; r2[tid] += r2[tid + off]; }
        __syncthreads();
    }
    if (tid == 0) {
        const double ntot  = (double)BC * (double)NVOX;
        double loss1 = r1[0] / ntot;
        double loss2 = r2[0] / ((double)NVOX * (double)(BC * KBINS));
        out[0] = (float)(0.5 * loss1 + 0.5 * loss2);
    }
}

extern "C" void kernel_launch(void* const* d_in, const int* in_sizes, int n_in,
                              void* d_out, int out_size, void* d_ws, size_t ws_size,
                              hipStream_t stream) {
    const float* inp = (const float*)d_in[0];
    const float* tar = (const float*)d_in[1];
    const float* br  = (const float*)d_in[2];

    int*   g_cdf    = (int*)d_ws;
    float* partials = (float*)((char*)d_ws + BC * NEDGE * sizeof(int));

    // CDF accumulators use atomics -> zero every call
    hipMemsetAsync(d_ws, 0, BC * NEDGE * sizeof(int), stream);

    binloss_main<<<NBLOCKS, THREADS, 0, stream>>>(inp, tar, br, g_cdf, partials);
    binloss_final<<<1, 256, 0, stream>>>(g_cdf, partials, (float*)d_out);
}

// Round 9
// 52.877 us; speedup vs baseline: 2.9082x; 2.9082x over previous
//
#include <hip/hip_runtime.h>

#define BC 88                        // B*C channels
#define NVOX 262144                  // 64^3
#define KBINS 20
#define THREADS 256
#define NBLOCKS 1024                 // 4/CU resident at launch_bounds(256,4); zero tail
#define CPB 22                       // chunks/block: 1024*22 = 22528 = BC*NVOX/1024
#define CPC 256                      // chunks per channel
#define HSTRIDE 23                   // 22 slots + pad; gcd(23,32)=1
#define NIBM64 0x0F0F0F0F0F0F0F0Full
#define NIBM32 0x000F0F0Fu

// bin j+1 (j in 0..19) -> (dword, byte) in the 6-dword byte-accumulator row
__device__ __forceinline__ int getbyte(const unsigned int* row, int set, int jj) {
    int dw, by;
    if (jj < 16) { int m = jj >> 1; dw = (jj & 1) * 2 + (m >> 2); by = m & 3; }
    else         { dw = 4 + (jj & 1); by = (jj - 16) >> 1; }
    return (int)((row[set * 6 + dw] >> (8 * by)) & 0xFFu);
}

// Hybrid: a-operand histogram via 1 ds_atomic/pair (DS pipe), b-operand via
// register nibble one-hot -> byte accumulators (VALU pipe). No global atomics:
// per-block slot writes (seg0 -> slot[blk], boundary seg1 -> bslot[ch]).
__global__ void __launch_bounds__(THREADS, 4)
binloss_main(const float* __restrict__ inp, const float* __restrict__ tar,
             const float* __restrict__ br, int* __restrict__ slot,
             int* __restrict__ bslot, float* __restrict__ partials)
{
    __shared__ int          dsrows[2][64][HSTRIDE];   // 11776 B
    __shared__ unsigned int brow[THREADS][13];        // 13312 B (12 + pad)
    __shared__ int          dsq[2][4][KBINS];
    __shared__ int          byq[2][4][KBINS];
    __shared__ float        wsum[THREADS / 64];

    const int tid  = threadIdx.x;
    const int lane = tid & 63;
    for (int i = tid; i < 2 * 64 * HSTRIDE; i += THREADS) ((int*)dsrows)[i] = 0;

    const float e0     = br[0];
    const float eK     = br[2 * KBINS - 1];
    const float inv_w  = (float)KBINS / (eK - e0);
    const float shift1 = 1.0f - e0 * inv_w;
    const float tmax   = 21.5f;
    __syncthreads();

    const int fc  = blockIdx.x * CPB;
    const int ch0 = fc >> 8;
    const int rem = fc & (CPC - 1);
    const int n1  = (rem + CPB > CPC) ? (CPC - rem) : CPB;   // chunks in ch0

    const float4* pa = (const float4*)inp + (size_t)fc * 256 + tid;
    const float4* pb = (const float4*)tar + (size_t)fc * 256 + tid;

    int* r0 = &dsrows[0][lane][0];
    int* r1 = &dsrows[1][lane][0];

    unsigned long long N0 = 0;  unsigned int N1 = 0;          // nibble acc (1 chunk)
    unsigned long long Be0 = 0, Bo0 = 0;  unsigned int Be1 = 0, Bo1 = 0;  // set0 bytes
    unsigned long long Ce0 = 0, Co0 = 0;  unsigned int Ce1 = 0, Co1 = 0;  // set1 bytes
    float s_lin = 0.f, s_quad = 0.f;

    float4 a = pa[0], b = pb[0];
#pragma unroll 2
    for (int k = 0; k < CPB; ++k) {
        float4 an, bn;
        if (k < CPB - 1) { an = pa[(k + 1) * 256]; bn = pb[(k + 1) * 256]; }
        int* rw = (k < n1) ? r0 : r1;                          // uniform select

#pragma unroll
        for (int q = 0; q < 4; ++q) {
            float av = (&a.x)[q], bv = (&b.x)[q];
            float d = fabsf(av - bv);
            s_lin += fmaxf(d, 1.0f);                           // -1 hoisted
            float m = fminf(d, 1.0f);
            s_quad  = __builtin_fmaf(m, m, s_quad);
            int sa = (int)__builtin_amdgcn_fmed3f(__builtin_fmaf(av, inv_w, shift1), 0.0f, tmax);
            int sb = (int)__builtin_amdgcn_fmed3f(__builtin_fmaf(bv, inv_w, shift1), 0.0f, tmax);
            atomicAdd(&rw[sa], 1);                             // DS pipe (+1)
            int k4 = sb << 2;                                  // VALU pipe (-1 at fold)
            unsigned long long P = 1ull << (k4 & 63);
            bool lo = (sb < 16);
            N0 += lo ? P : 0ull;
            N1 += lo ? 0u : (unsigned int)P;                   // sb>=16: bit in P.lo
        }
        // flush nibbles (<=4/slot) into the chunk's segment byte-set
        {
            unsigned long long fe = N0 & NIBM64, fo = (N0 >> 4) & NIBM64;
            unsigned int fe1 = N1 & NIBM32, fo1 = (N1 >> 4) & NIBM32;
            if (k < n1) { Be0 += fe; Bo0 += fo; Be1 += fe1; Bo1 += fo1; }
            else        { Ce0 += fe; Co0 += fo; Ce1 += fe1; Co1 += fo1; }
            N0 = 0; N1 = 0;
        }
        a = an; b = bn;
    }

    // dump byte accumulators
    unsigned int* myrow = &brow[tid][0];
    myrow[0] = (unsigned int)Be0;  myrow[1] = (unsigned int)(Be0 >> 32);
    myrow[2] = (unsigned int)Bo0;  myrow[3] = (unsigned int)(Bo0 >> 32);
    myrow[4] = Be1;                myrow[5] = Bo1;
    myrow[6] = (unsigned int)Ce0;  myrow[7] = (unsigned int)(Ce0 >> 32);
    myrow[8] = (unsigned int)Co0;  myrow[9] = (unsigned int)(Co0 >> 32);
    myrow[10] = Ce1;               myrow[11] = Co1;

    // SmoothL1 wave reduce
    float sl1 = (s_lin - (float)(CPB * 4)) + 0.5f * s_quad;
#pragma unroll
    for (int off = 32; off > 0; off >>= 1) sl1 += __shfl_down(sl1, off, 64);
    if (lane == 0) wsum[tid >> 6] = sl1;
    __syncthreads();

    // stage 1: quarter sums (DS rows +, byte rows -) for both segments
    if (tid < 160) {
        const int set = tid / 80, r = tid % 80;
        const int qr = r / KBINS, j = r % KBINS;           // bin = j+1
        int ds = 0;
#pragma unroll
        for (int rr = qr * 16; rr < qr * 16 + 16; ++rr) ds += dsrows[set][rr][j + 1];
        int bs = 0;
        for (int th = qr * 64; th < qr * 64 + 64; ++th) bs += getbyte(&brow[th][0], set, j + 1);
        dsq[set][qr][j] = ds;
        byq[set][qr][j] = bs;
    }
    if (tid == 0)
        partials[blockIdx.x] = wsum[0] + wsum[1] + wsum[2] + wsum[3];
    __syncthreads();

    // stage 2: combine quarters; write per-block / per-channel slots (no atomics)
    if (tid < 2 * KBINS) {
        const int set = tid / KBINS, j = tid % KBINS;
        int v = dsq[set][0][j] + dsq[set][1][j] + dsq[set][2][j] + dsq[set][3][j]
              - byq[set][0][j] - byq[set][1][j] - byq[set][2][j] - byq[set][3][j];
        if (set == 0)            slot[blockIdx.x * KBINS + j] = v;
        else if (n1 < CPB)       bslot[(ch0 + 1) * KBINS + j] = v;
    }
    if (rem == 0 && tid < KBINS) bslot[ch0 * KBINS + tid] = 0;  // aligned channels
}

__global__ void __launch_bounds__(256)
binloss_final(const int* __restrict__ slot, const int* __restrict__ bslot,
              const float* __restrict__ partials, float* __restrict__ out)
{
    __shared__ double r1[256];
    __shared__ double r2[256];
    const int tid = threadIdx.x;
    double s1 = 0.0, s2 = 0.0;
    for (int i = tid; i < NBLOCKS; i += 256) s1 += (double)partials[i];
    for (int i = tid; i < BC * KBINS; i += 256) {
        const int c = i / KBINS, j = i - c * KBINS;
        const int b0 = (CPC * c + CPB - 1) / CPB;           // first block with ch0==c
        const int b1 = (CPC * (c + 1) + CPB - 1) / CPB;
        int s = bslot[c * KBINS + j];
        for (int b = b0; b < b1; ++b) s += slot[b * KBINS + j];
        s2 += fabs((double)s);
    }
    r1[tid] = s1; r2[tid] = s2;
    __syncthreads();
    for (int off = 128; off > 0; off >>= 1) {
        if (tid < off) { r1[tid] += r1[tid + off]; r2[tid] += r2[tid + off]; }
        __syncthreads();
    }
    if (tid == 0) {
        const double ntot  = (double)BC * (double)NVOX;
        double loss1 = r1[0] / ntot;
        double loss2 = r2[0] / ((double)NVOX * (double)(BC * KBINS));
        out[0] = (float)(0.5 * loss1 + 0.5 * loss2);
    }
}

extern "C" void kernel_launch(void* const* d_in, const int* in_sizes, int n_in,
                              void* d_out, int out_size, void* d_ws, size_t ws_size,
                              hipStream_t stream) {
    const float* inp = (const float*)d_in[0];
    const float* tar = (const float*)d_in[1];
    const float* br  = (const float*)d_in[2];

    int*   slot     = (int*)d_ws;                                  // 1024*20 ints
    int*   bslot    = slot + NBLOCKS * KBINS;                      // 88*20 ints
    float* partials = (float*)(bslot + BC * KBINS);                // 1024 floats
    // every ws byte above is unconditionally written each call -> no memset

    binloss_main<<<NBLOCKS, THREADS, 0, stream>>>(inp, tar, br, slot, bslot, partials);
    binloss_final<<<1, 256, 0, stream>>>(slot, bslot, partials, (float*)d_out);
}

// Round 10
// 51.411 us; speedup vs baseline: 2.9912x; 1.0285x over previous
//
#include <hip/hip_runtime.h>

#define BC 88                        // B*C channels
#define NVOX 262144                  // 64^3
#define KBINS 20
#define THREADS 256
#define NBLOCKS 1024                 // 4/CU, fully resident, zero tail
#define CPB 22                       // chunks/block: 1024*22*1024 = 23.07M elems
#define CPC 256                      // chunks per channel
#define HSTRIDE 23                   // 22 slots + pad; gcd(23,32)=1
#define ROWSET (64 * HSTRIDE)

// R6/R7 lean inner loop (verified absmax 0.0) + R9's no-atomic/no-memset slot
// epilogue. Every workspace byte is written every call (poison-safe).
__global__ void __launch_bounds__(THREADS)
binloss_main(const float* __restrict__ inp, const float* __restrict__ tar,
             const float* __restrict__ br, int* __restrict__ slot,
             int* __restrict__ bslot, float* __restrict__ partials)
{
    __shared__ int   rows[2 * ROWSET];        // 11776 B: seg0 / seg1 rowsets
    __shared__ int   qsum[2][4][KBINS];
    __shared__ float wsum[THREADS / 64];

    const int tid  = threadIdx.x;
    const int lane = tid & 63;
    for (int i = tid; i < 2 * ROWSET; i += THREADS) rows[i] = 0;

    // uniform scalar loads; +1 folded so (int) truncation == floor
    const float e0     = br[0];
    const float eK     = br[2 * KBINS - 1];
    const float inv_w  = (float)KBINS / (eK - e0);
    const float shift1 = 1.0f - e0 * inv_w;
    const float tmax   = 21.5f;
    __syncthreads();

    const int fc  = blockIdx.x * CPB;
    const int ch0 = fc >> 8;                  // / CPC
    const int rem = fc & (CPC - 1);
    const int n1  = (rem + CPB > CPC) ? (CPC - rem) : CPB;   // chunks in ch0

    const float4* pa = (const float4*)inp + (size_t)fc * 256 + tid;
    const float4* pb = (const float4*)tar + (size_t)fc * 256 + tid;

    int* r0 = &rows[lane * HSTRIDE];
    int* r1 = r0 + ROWSET;

    float s_lin = 0.f, s_quad = 0.f;

#pragma unroll 2
    for (int k = 0; k < CPB; ++k) {
        float4 a = pa[k * 256];
        float4 b = pb[k * 256];
        int* rw = (k < n1) ? r0 : r1;                        // uniform select
#pragma unroll
        for (int q = 0; q < 4; ++q) {
            float av = (&a.x)[q], bv = (&b.x)[q];
            float d = fabsf(av - bv);
            s_lin += fmaxf(d, 1.0f);                         // -1 hoisted out
            float m = fminf(d, 1.0f);
            s_quad  = __builtin_fmaf(m, m, s_quad);
            int sa = (int)__builtin_amdgcn_fmed3f(__builtin_fmaf(av, inv_w, shift1), 0.0f, tmax);
            int sb = (int)__builtin_amdgcn_fmed3f(__builtin_fmaf(bv, inv_w, shift1), 0.0f, tmax);
            atomicAdd(&rw[sa], 1);                           // slots 0,21 = trash
            atomicAdd(&rw[sb], -1);
        }
    }

    // SmoothL1 wave(64) + cross-wave reduce
    float sl1 = (s_lin - (float)(CPB * 4)) + 0.5f * s_quad;
#pragma unroll
    for (int off = 32; off > 0; off >>= 1) sl1 += __shfl_down(sl1, off, 64);
    if (lane == 0) wsum[tid >> 6] = sl1;
    __syncthreads();

    // stage 1: 160 threads sum 16 rows each (set x quarter x bin)
    if (tid < 160) {
        const int set = tid / 80, r = tid % 80;
        const int qr = r / KBINS, j = r % KBINS;
        int s = 0;
#pragma unroll
        for (int rr = qr * 16; rr < qr * 16 + 16; ++rr)
            s += rows[set * ROWSET + rr * HSTRIDE + 1 + j];
        qsum[set][qr][j] = s;
    }
    if (tid == 0)
        partials[blockIdx.x] = wsum[0] + wsum[1] + wsum[2] + wsum[3];
    __syncthreads();

    // stage 2: combine quarters; plain slot writes (no atomics, no memset)
    if (tid < 2 * KBINS) {
        const int set = tid / KBINS, j = tid % KBINS;
        int v = qsum[set][0][j] + qsum[set][1][j] + qsum[set][2][j] + qsum[set][3][j];
        if (set == 0)          slot[blockIdx.x * KBINS + j] = v;     // seg0 -> ch0
        else if (n1 < CPB)     bslot[(ch0 + 1) * KBINS + j] = v;     // seg1 -> ch0+1
    }
    if (rem == 0 && tid < KBINS) bslot[ch0 * KBINS + tid] = 0;       // aligned start
}

__global__ void __launch_bounds__(256)
binloss_final(const int* __restrict__ slot, const int* __restrict__ bslot,
              const float* __restrict__ partials, float* __restrict__ out)
{
    __shared__ double r1[256];
    __shared__ double r2[256];
    const int tid = threadIdx.x;
    double s1 = 0.0, s2 = 0.0;
    for (int i = tid; i < NBLOCKS; i += 256) s1 += (double)partials[i];
    for (int i = tid; i < BC * KBINS; i += 256) {
        const int c = i / KBINS, j = i - c * KBINS;
        const int b0 = (128 * c + 10) / 11;                 // ceil(128c/11)
        const int b1 = (128 * (c + 1) + 10) / 11;
        int s = bslot[c * KBINS + j];
        for (int b = b0; b < b1; ++b) s += slot[b * KBINS + j];
        s2 += fabs((double)s);
    }
    r1[tid] = s1; r2[tid] = s2;
    __syncthreads();
    for (int off = 128; off > 0; off >>= 1) {
        if (tid < off) { r1[tid] += r1[tid + off]; r2[tid] += r2[tid + off]; }
        __syncthreads();
    }
    if (tid == 0) {
        const double ntot  = (double)BC * (double)NVOX;
        double loss1 = r1[0] / ntot;
        double loss2 = r2[0] / ((double)NVOX * (double)(BC * KBINS));
        out[0] = (float)(0.5 * loss1 + 0.5 * loss2);
    }
}

extern "C" void kernel_launch(void* const* d_in, const int* in_sizes, int n_in,
                              void* d_out, int out_size, void* d_ws, size_t ws_size,
                              hipStream_t stream) {
    const float* inp = (const float*)d_in[0];
    const float* tar = (const float*)d_in[1];
    const float* br  = (const float*)d_in[2];

    int*   slot     = (int*)d_ws;                         // 1024*20 ints (80 KB)
    int*   bslot    = slot + NBLOCKS * KBINS;             // 88*20 ints
    float* partials = (float*)(bslot + BC * KBINS);       // 1024 floats
    // every ws byte above is written unconditionally each call -> no memset

    binloss_main<<<NBLOCKS, THREADS, 0, stream>>>(inp, tar, br, slot, bslot, partials);
    binloss_final<<<1, 256, 0, stream>>>(slot, bslot, partials, (float*)d_out);
}